// Round 9
// baseline (436.606 us; speedup 1.0000x reference)
//
#include <hip/hip_runtime.h>

// ForgetMult: h_t = f_t*x_t + (1-f_t)*h_{t-1}, shapes (S=4096, B=16, H=512) fp32.
// R12: R11's fused kernel, launched as a REGULAR kernel (graph-capturable).
// Evidence (R11): profiled fm_fused = 263us (custom barrier works; all phases
// + 4 barriers), but timed dur = 375us -> the cooperative-launch path isn't
// what the harness times (coop launches aren't graph-capturable). Fix: plain
// <<<256,512>>> launch; co-residency is guaranteed by capacity (VGPR=68,
// LDS=0 -> >=3 blocks/CU; 256 blocks over 256 CUs). Also: P2b merged into
// P2c (each thread scans <=15 preceding segment aggregates from hot L2 for
// its own segment-entry h; identical arithmetic) -> 3 barriers instead of 4.

#define SQ      4096
#define NC4     2048            // float4 columns = 16*512/4
#define NCH     8192            // scalar chains
#define TT      32              // timesteps per chunk
#define NCHUNK  (SQ / TT)       // 128
#define NBLK    256
#define SEGS    16
#define CPS     (NCHUNK / SEGS) // 8 chunks per segment

// ws offsets (bytes)
#define AGGA_OFF  0u
#define AGGB_OFF  4194304u              // 4 MB  (NCHUNK*NC4*16)
#define SEGA_OFF  8388608u              // 512 KB
#define SEGB_OFF  8912896u              // 512 KB
#define BAR_OFF   9437184u              // 2 KB barrier region
#define WS_NEED   (BAR_OFF + 2048u)

typedef float floatx4 __attribute__((ext_vector_type(4)));

#define FM_B(B,F,X) \
  B.x = fmaf(F.x, X.x - B.x, B.x); B.y = fmaf(F.y, X.y - B.y, B.y); \
  B.z = fmaf(F.z, X.z - B.z, B.z); B.w = fmaf(F.w, X.w - B.w, B.w);
#define FM_A(A,F) \
  A.x = fmaf(-F.x, A.x, A.x); A.y = fmaf(-F.y, A.y, A.y); \
  A.z = fmaf(-F.z, A.z, A.z); A.w = fmaf(-F.w, A.w, A.w);

__device__ __forceinline__ void grid_barrier(unsigned* bar, int gen)
{
  __syncthreads();                      // block-local drain
  if (threadIdx.x == 0) {
    __threadfence();                    // device-scope release (L2 writeback)
    __hip_atomic_fetch_add(&bar[(gen * 8 + (blockIdx.x & 7)) * 16], 1u,
                           __ATOMIC_RELEASE, __HIP_MEMORY_SCOPE_AGENT);
    unsigned sum;
    do {
      sum = 0;
#pragma unroll
      for (int s = 0; s < 8; ++s)
        sum += __hip_atomic_load(&bar[(gen * 8 + s) * 16],
                                 __ATOMIC_RELAXED, __HIP_MEMORY_SCOPE_AGENT);
      if (sum < (unsigned)NBLK) __builtin_amdgcn_s_sleep(8);
    } while (sum < (unsigned)NBLK);
    __threadfence();                    // device-scope acquire (invalidate)
  }
  __syncthreads();
}

__global__ __launch_bounds__(512, 2)
void fm_fused(const floatx4* __restrict__ f4, const floatx4* __restrict__ x4,
              const float* __restrict__ h0, char* __restrict__ ws,
              floatx4* __restrict__ out4)
{
  floatx4*  aggA4 = (floatx4*)(ws + AGGA_OFF);
  floatx4*  aggB4 = (floatx4*)(ws + AGGB_OFF);
  float*    aggAs = (float*)(ws + AGGA_OFF);
  float*    aggBs = (float*)(ws + AGGB_OFF);
  float*    segA  = (float*)(ws + SEGA_OFF);
  float*    segB  = (float*)(ws + SEGB_OFF);
  unsigned* bar   = (unsigned*)(ws + BAR_OFF);

  const int bid = blockIdx.x, tid = threadIdx.x;
  const int chunk = bid >> 1;
  const int c0 = ((bid & 1) << 10) + tid;       // this block's first col
  const int c1 = c0 + 512;                      // second col
  const size_t tbase = (size_t)chunk * TT * NC4;

  // ---- P1: per-chunk aggregates A = prod(1-f), B = local scan ----
  {
    floatx4 A0 = {1.f,1.f,1.f,1.f}, A1 = {1.f,1.f,1.f,1.f};
    floatx4 B0 = {0.f,0.f,0.f,0.f}, B1 = {0.f,0.f,0.f,0.f};
#pragma unroll 8
    for (int t = 0; t < TT; ++t) {
      const size_t r = tbase + (size_t)t * NC4;
      const floatx4 F0 = f4[r + c0], X0 = x4[r + c0];
      const floatx4 F1 = f4[r + c1], X1 = x4[r + c1];
      FM_B(B0, F0, X0)  FM_A(A0, F0)
      FM_B(B1, F1, X1)  FM_A(A1, F1)
    }
    aggA4[(size_t)chunk * NC4 + c0] = A0;
    aggA4[(size_t)chunk * NC4 + c1] = A1;
    aggB4[(size_t)chunk * NC4 + c0] = B0;
    aggB4[(size_t)chunk * NC4 + c1] = B1;
  }
  grid_barrier(bar, 0);

  // ---- P2a: segment aggregates (16 segs x 8 chunks), all 131072 threads ----
  {
    const int g = bid * 512 + tid;
    const int chain = g & (NCH - 1);
    const int seg   = g >> 13;
    float a = 1.f, b = 0.f;
#pragma unroll
    for (int i = 0; i < CPS; ++i) {
      const size_t idx = (size_t)(seg * CPS + i) * NCH + chain;
      const float ac = aggAs[idx], bc = aggBs[idx];
      b = fmaf(ac, b, bc);
      a *= ac;
    }
    segA[seg * NCH + chain] = a;
    segB[seg * NCH + chain] = b;
  }
  grid_barrier(bar, 1);

  // ---- P2c: segment-entry h (scan of preceding segment aggregates, hot L2)
  //          then within-segment scan -> hprev written in place into aggB ----
  {
    const int g = bid * 512 + tid;
    const int chain = g & (NCH - 1);
    const int seg   = g >> 13;

    float h = h0[chain];
    for (int s = 0; s < seg; ++s)                  // <=15 iters, L2-resident
      h = fmaf(segA[s * NCH + chain], h, segB[s * NCH + chain]);

    float a[CPS], b[CPS];
#pragma unroll
    for (int i = 0; i < CPS; ++i) {
      const size_t idx = (size_t)(seg * CPS + i) * NCH + chain;
      a[i] = aggAs[idx];
      b[i] = aggBs[idx];
    }
#pragma unroll
    for (int i = 0; i < CPS; ++i) {
      const size_t idx = (size_t)(seg * CPS + i) * NCH + chain;
      aggBs[idx] = h;                              // hprev entering this chunk
      h = fmaf(a[i], h, b[i]);
    }
  }
  grid_barrier(bar, 2);

  // ---- P3: apply recurrence from hprev (= aggB), NT out stores ----
  {
    floatx4 H0 = aggB4[(size_t)chunk * NC4 + c0];
    floatx4 H1 = aggB4[(size_t)chunk * NC4 + c1];
#pragma unroll 8
    for (int t = 0; t < TT; ++t) {
      const size_t r = tbase + (size_t)t * NC4;
      const floatx4 F0 = f4[r + c0], X0 = x4[r + c0];
      const floatx4 F1 = f4[r + c1], X1 = x4[r + c1];
      FM_B(H0, F0, X0)
      FM_B(H1, F1, X1)
      __builtin_nontemporal_store(H0, &out4[r + c0]);
      __builtin_nontemporal_store(H1, &out4[r + c1]);
    }
  }
}

// ---------------- fallback: proven 3-kernel path (R6, TT=16) ----------------
#define FTT     16
#define FNCHUNK (SQ / FTT)      // 256

__global__ __launch_bounds__(256, 4)
void fm_agg(const floatx4* __restrict__ f4, const floatx4* __restrict__ x4,
            floatx4* __restrict__ aggA, floatx4* __restrict__ aggB)
{
  const int tid   = threadIdx.x;
  const int chunk = blockIdx.x >> 3;
  const int col   = ((blockIdx.x & 7) << 8) + tid;
  const size_t base = (size_t)(chunk * FTT) * NC4 + col;

  floatx4 A = {1.f,1.f,1.f,1.f}, B = {0.f,0.f,0.f,0.f};
#pragma unroll 8
  for (int t = 0; t < FTT; ++t) {
    const floatx4 F = f4[base + (size_t)t * NC4];
    const floatx4 X = x4[base + (size_t)t * NC4];
    FM_B(B, F, X)  FM_A(A, F)
  }
  aggA[(size_t)chunk * NC4 + col] = A;
  aggB[(size_t)chunk * NC4 + col] = B;
}

__global__ __launch_bounds__(256, 4)
void fm_mid(const float* __restrict__ A, float* __restrict__ B,
            const float* __restrict__ h0)
{
  const int chain = blockIdx.x * 256 + threadIdx.x;
  float h = h0[chain];
  for (int cb = 0; cb < FNCHUNK / 16; ++cb) {
    float a[16], b[16];
#pragma unroll
    for (int i = 0; i < 16; ++i) {
      const size_t idx = (size_t)(cb * 16 + i) * NCH + chain;
      a[i] = A[idx];
      b[i] = B[idx];
    }
#pragma unroll
    for (int i = 0; i < 16; ++i) {
      const size_t idx = (size_t)(cb * 16 + i) * NCH + chain;
      B[idx] = h;
      h = fmaf(a[i], h, b[i]);
    }
  }
}

__global__ __launch_bounds__(256, 4)
void fm_apply(const floatx4* __restrict__ f4, const floatx4* __restrict__ x4,
              const floatx4* __restrict__ hprev4, floatx4* __restrict__ out4)
{
  const int tid   = threadIdx.x;
  const int chunk = (FNCHUNK - 1) - (blockIdx.x >> 3);
  const int col   = ((blockIdx.x & 7) << 8) + tid;
  const size_t base = (size_t)(chunk * FTT) * NC4 + col;

  floatx4 h = hprev4[(size_t)chunk * NC4 + col];
#pragma unroll 8
  for (int t = 0; t < FTT; ++t) {
    const floatx4 F = f4[base + (size_t)t * NC4];
    const floatx4 X = x4[base + (size_t)t * NC4];
    FM_B(h, F, X)
    __builtin_nontemporal_store(h, &out4[base + (size_t)t * NC4]);
  }
}

__global__ void fm_naive(const floatx4* __restrict__ f4, const floatx4* __restrict__ x4,
                         const floatx4* __restrict__ h04, floatx4* __restrict__ out4)
{
  const int col = blockIdx.x * blockDim.x + threadIdx.x;
  if (col >= NC4) return;
  floatx4 h = h04[col];
  for (int t = 0; t < SQ; ++t) {
    const size_t idx = (size_t)t * NC4 + col;
    const floatx4 F = f4[idx], X = x4[idx];
    FM_B(h, F, X)
    out4[idx] = h;
  }
}

extern "C" void kernel_launch(void* const* d_in, const int* in_sizes, int n_in,
                              void* d_out, int out_size, void* d_ws, size_t ws_size,
                              hipStream_t stream)
{
  const floatx4* f4  = (const floatx4*)d_in[0];
  const floatx4* x4  = (const floatx4*)d_in[1];
  const float*   h0  = (const float*)d_in[2];
  floatx4* out4 = (floatx4*)d_out;

  if (ws_size >= WS_NEED) {
    char* ws = (char*)d_ws;
    hipMemsetAsync(ws + BAR_OFF, 0, 2048, stream);    // zero barrier counters
    fm_fused<<<NBLK, 512, 0, stream>>>(f4, x4, h0, ws, out4);
    return;
  }

  const size_t AGG = (size_t)FNCHUNK * NC4 * 16;      // 8 MB per aggregate array
  if (ws_size >= 2 * AGG) {                           // 16 MB: proven 3-kernel
    floatx4* aggA = (floatx4*)d_ws;
    floatx4* aggB = (floatx4*)((char*)d_ws + AGG);
    fm_agg<<<FNCHUNK * 8, 256, 0, stream>>>(f4, x4, aggA, aggB);
    fm_mid<<<NCH / 256, 256, 0, stream>>>((const float*)aggA,
                                          (float*)aggB, h0);
    fm_apply<<<FNCHUNK * 8, 256, 0, stream>>>(f4, x4, (const floatx4*)aggB, out4);
  } else {
    fm_naive<<<(NC4 + 255) / 256, 256, 0, stream>>>(f4, x4,
                                                    (const floatx4*)h0, out4);
  }
}

// Round 10
// 361.311 us; speedup vs baseline: 1.2084x; 1.2084x over previous
//
#include <hip/hip_runtime.h>

// ForgetMult: h_t = f_t*x_t + (1-f_t)*h_{t-1}, shapes (S=4096, B=16, H=512) fp32.
// R13: window-clustered 3-kernel scan. Measurement model (R12): dur_us =
// kernel-sum + ~190us fixed harness overhead; fused-1-kernel = 247us > 3-kernel
// sum 182us => back to 3 kernels. Remaining lever: P1's ~2.6 TB/s wall. Theory:
// DRAM row-buffer thrash from instantaneous access spread (2048 blocks at 2048
// 32KB-spaced positions = every access opens a new row; the 6.3 TB/s copy bench
// sweeps a clustered ~2MB front). Fix: TT=64, NCHUNK=64, grid=512 (4 blk/CU):
// only 64 row-windows active at once, each = 8 blocks cooperatively sweeping
// one contiguous 32KB row then advancing => ~128 long sequential streams.
// Mid: 64-step in-place scan (hprev into aggB). P3: descending chunks, NT out.

#define SQ      4096
#define NC4     2048            // float4 columns = 16*512/4
#define NCH     8192            // scalar chains
#define TT      64              // timesteps per chunk
#define NCHUNK  (SQ / TT)       // 64
#define GRID1   (NCHUNK * 8)    // 512 blocks for K1/K3

typedef float floatx4 __attribute__((ext_vector_type(4)));

#define FM_B(B,F,X) \
  B.x = fmaf(F.x, X.x - B.x, B.x); B.y = fmaf(F.y, X.y - B.y, B.y); \
  B.z = fmaf(F.z, X.z - B.z, B.z); B.w = fmaf(F.w, X.w - B.w, B.w);
#define FM_A(A,F) \
  A.x = fmaf(-F.x, A.x, A.x); A.y = fmaf(-F.y, A.y, A.y); \
  A.z = fmaf(-F.z, A.z, A.z); A.w = fmaf(-F.w, A.w, A.w);

// ---- K1: per-chunk aggregates A = prod(1-f), B = local scan ----
// block b -> chunk b>>3, col-block b&7. 64 chunks concurrently resident;
// each chunk's 8 blocks sweep rows t=0..63 together (clustered 32KB front).
__global__ __launch_bounds__(256, 4)
void fm_agg(const floatx4* __restrict__ f4, const floatx4* __restrict__ x4,
            floatx4* __restrict__ aggA, floatx4* __restrict__ aggB)
{
  const int tid   = threadIdx.x;
  const int chunk = blockIdx.x >> 3;
  const int col   = ((blockIdx.x & 7) << 8) + tid;
  const size_t base = (size_t)(chunk * TT) * NC4 + col;

  floatx4 A = {1.f,1.f,1.f,1.f}, B = {0.f,0.f,0.f,0.f};
#pragma unroll 8
  for (int t = 0; t < TT; ++t) {
    const floatx4 F = f4[base + (size_t)t * NC4];
    const floatx4 X = x4[base + (size_t)t * NC4];
    FM_B(B, F, X)  FM_A(A, F)
  }
  aggA[(size_t)chunk * NC4 + col] = A;
  aggB[(size_t)chunk * NC4 + col] = B;
}

// ---- K2: scan chunk aggregates per scalar chain, hprev written IN PLACE ----
// Scalar view of aggA/aggB: [chunk][8192 chains]. For each chunk c: read (a,b),
// store incoming h into the B slot (becomes hprev for K3), advance h = a*h+b.
__global__ __launch_bounds__(256, 4)
void fm_mid(const float* __restrict__ A, float* __restrict__ B,
            const float* __restrict__ h0)
{
  const int chain = blockIdx.x * 256 + threadIdx.x;
  float h = h0[chain];
  for (int cb = 0; cb < NCHUNK / 16; ++cb) {
    float a[16], b[16];
#pragma unroll
    for (int i = 0; i < 16; ++i) {
      const size_t idx = (size_t)(cb * 16 + i) * NCH + chain;
      a[i] = A[idx];
      b[i] = B[idx];
    }
#pragma unroll
    for (int i = 0; i < 16; ++i) {
      const size_t idx = (size_t)(cb * 16 + i) * NCH + chain;
      B[idx] = h;                    // hprev entering chunk cb*16+i
      h = fmaf(a[i], h, b[i]);
    }
  }
}

// ---- K3: apply recurrence from hprev (= aggB), descending chunks, NT out ----
__global__ __launch_bounds__(256, 4)
void fm_apply(const floatx4* __restrict__ f4, const floatx4* __restrict__ x4,
              const floatx4* __restrict__ hprev4, floatx4* __restrict__ out4)
{
  const int tid   = threadIdx.x;
  const int chunk = (NCHUNK - 1) - (blockIdx.x >> 3);   // descending: LLC reuse
  const int col   = ((blockIdx.x & 7) << 8) + tid;
  const size_t base = (size_t)(chunk * TT) * NC4 + col;

  floatx4 h = hprev4[(size_t)chunk * NC4 + col];
#pragma unroll 8
  for (int t = 0; t < TT; ++t) {
    const floatx4 F = f4[base + (size_t)t * NC4];
    const floatx4 X = x4[base + (size_t)t * NC4];
    FM_B(h, F, X)
    // Nontemporal: don't let the 128 MB output stream evict f,x from LLC.
    __builtin_nontemporal_store(h, &out4[base + (size_t)t * NC4]);
  }
}

// Fallback (only if ws_size is too small): one float4-column per thread.
__global__ void fm_naive(const floatx4* __restrict__ f4, const floatx4* __restrict__ x4,
                         const floatx4* __restrict__ h04, floatx4* __restrict__ out4)
{
  const int col = blockIdx.x * blockDim.x + threadIdx.x;
  if (col >= NC4) return;
  floatx4 h = h04[col];
  for (int t = 0; t < SQ; ++t) {
    const size_t idx = (size_t)t * NC4 + col;
    const floatx4 F = f4[idx], X = x4[idx];
    FM_B(h, F, X)
    out4[idx] = h;
  }
}

extern "C" void kernel_launch(void* const* d_in, const int* in_sizes, int n_in,
                              void* d_out, int out_size, void* d_ws, size_t ws_size,
                              hipStream_t stream)
{
  const floatx4* f4  = (const floatx4*)d_in[0];
  const floatx4* x4  = (const floatx4*)d_in[1];
  const float*   h0  = (const float*)d_in[2];
  floatx4* out4 = (floatx4*)d_out;

  const size_t AGG = (size_t)NCHUNK * NC4 * 16;   // 2 MB per aggregate array

  if (ws_size >= 2 * AGG) {                        // 4 MB needed
    floatx4* aggA = (floatx4*)d_ws;
    floatx4* aggB = (floatx4*)((char*)d_ws + AGG);
    fm_agg<<<GRID1, 256, 0, stream>>>(f4, x4, aggA, aggB);
    fm_mid<<<NCH / 256, 256, 0, stream>>>((const float*)aggA,
                                          (float*)aggB, h0);
    fm_apply<<<GRID1, 256, 0, stream>>>(f4, x4, (const floatx4*)aggB, out4);
  } else {
    fm_naive<<<(NC4 + 255) / 256, 256, 0, stream>>>(f4, x4,
                                                    (const floatx4*)h0, out4);
  }
}